// Round 6
// baseline (354.501 us; speedup 1.0000x reference)
//
#include <hip/hip_runtime.h>

#define B_ 16
#define C_ 512
#define S_ 128
#define T_ 2048
#define HALF 18
#define WLEN 37

typedef __bf16 bf16x8 __attribute__((ext_vector_type(8)));
typedef float f32x4 __attribute__((ext_vector_type(4)));
typedef float f32x16 __attribute__((ext_vector_type(16)));
typedef unsigned short ushort_t;

__device__ inline ushort_t f2bf(float x) {
    unsigned u = __float_as_uint(x);
    u += 0x7fffu + ((u >> 16) & 1u);  // RNE; inputs are finite
    return (ushort_t)(u >> 16);
}
__device__ inline float bf2f(ushort_t h) {
    return __uint_as_float(((unsigned)h) << 16);
}
__device__ inline float fast_tanh(float z) {
    float e = __expf(2.f * z);
    return 1.f - __fdividef(2.f, e + 1.f);
}
__device__ __forceinline__ void glds16(const void* g, void* l) {
    __builtin_amdgcn_global_load_lds(
        (const __attribute__((address_space(1))) unsigned*)g,
        (__attribute__((address_space(3))) unsigned*)l, 16, 0, 0);
}

#define MFMA16(a, b, c) __builtin_amdgcn_mfma_f32_16x16x32_bf16((a), (b), (c), 0, 0, 0)
#define MFMA32(a, b, c) __builtin_amdgcn_mfma_f32_32x32x16_bf16((a), (b), (c), 0, 0, 0)

// Conv image geometry: per conv [ob(4)][cc(32)] chunks of 14336 B.
// Each chunk IS the LDS A-tile [128 rows][112 B]: row = o-local, byte col
// c = tap*32 + kh*16 + ch2*2 holds w[o=ob*128+row][i=cc*16+kh*8+ch2][tap];
// bytes 96..111 of each row zero pad (7 granules/row, odd -> conflict-free).
#define ACH_BYTES 14336  // 14 x 1024
#define BCH_BYTES 7168   // 7 x 1024 (130 rows x 48 B = 6240 used)
#define CH_BYTES (ACH_BYTES + BCH_BYTES)  // 21504; dbuf = 43008 -> 3 blocks/CU

// ---------------- fused prep kernel: winsum + conv images + fc weights + pads --
__global__ __launch_bounds__(256) void prep_all(
    const float* __restrict__ s, ushort_t* __restrict__ sw_t,
    const float* __restrict__ fc1, const float* __restrict__ fc2,
    ushort_t* __restrict__ Wfc, const float* __restrict__ c1,
    const float* __restrict__ c2, ushort_t* __restrict__ I1,
    ushort_t* __restrict__ I2, ushort_t* __restrict__ y1p,
    ushort_t* __restrict__ y2p) {
    __shared__ float sb[128][101];
    int bid = blockIdx.x;
    int tid = threadIdx.x;
    if (bid < 512) {
        // ---- winsum(s) over t, output transposed: sw_t[b][t][s] bf16 ----
        int b = bid >> 5;
        int t0 = (bid & 31) * 64;
        for (int e = tid; e < 128 * 100; e += 256) {
            int sj = e / 100;
            int u = e - sj * 100;
            int gt = t0 - HALF + u;
            float v = 0.f;
            if (gt >= 0 && gt < T_) v = s[((size_t)(b * S_ + sj)) * T_ + gt];
            sb[sj][u] = v;
        }
        __syncthreads();
        for (int e = tid; e < 64 * 128; e += 256) {
            int tl = e >> 7;
            int sj = e & 127;
            float sum = 0.f;
#pragma unroll
            for (int d = 0; d < WLEN; ++d) sum += sb[sj][tl + d];
            sw_t[((size_t)(b * T_ + t0 + tl)) * S_ + sj] = f2bf(sum);
        }
    } else if (bid < 1408) {
        // ---- conv weight images ([ob][cc] x [128][112] layout) ----
        int idx = (bid - 512) * 256 + tid;            // 16-B slot id
        const int per_conv = 4 * 32 * 896;            // 114688 slots
        int conv = idx >= per_conv;
        int rr = conv ? idx - per_conv : idx;
        const float* src = conv ? c2 : c1;
        ushort_t* dst = conv ? I2 : I1;
        int chunk_id = rr / 896;                      // 0..127
        int srem = rr - chunk_id * 896;
        int ob = chunk_id >> 5, cc = chunk_id & 31;
        int off = srem * 16;
        int row = off / 112;
        int c = off - row * 112;                      // multiple of 16
        ushort_t vals[8];
        if (c >= 96) {
#pragma unroll
            for (int e = 0; e < 8; ++e) vals[e] = 0;
        } else {
            int tap = c >> 5;
            int kh8 = (c & 16) ? 8 : 0;
            int o = ob * 128 + row;
            int ibase = cc * 16 + kh8;
#pragma unroll
            for (int e = 0; e < 8; ++e)
                vals[e] = f2bf(src[(size_t)(o * 512 + ibase + e) * 3 + tap]);
        }
        uint4 pk;
        pk.x = vals[0] | ((unsigned)vals[1] << 16);
        pk.y = vals[2] | ((unsigned)vals[3] << 16);
        pk.z = vals[4] | ((unsigned)vals[5] << 16);
        pk.w = vals[6] | ((unsigned)vals[7] << 16);
        *(uint4*)&dst[(size_t)rr * 8] = pk;
    } else if (bid < 2432) {
        // ---- fc weights fp32 -> bf16 ----
        const int n_fc = 1024 * 128;
        int idx = (bid - 1408) * 256 + tid;
        if (idx < n_fc) Wfc[idx] = f2bf(fc1[idx]);
        else if (idx < 2 * n_fc) Wfc[idx] = f2bf(fc2[idx - n_fc]);
    } else {
        // ---- zero halo rows (t=-1, t=T) of both padded buffers ----
        int t2 = (bid - 2432) * 256 + tid;
        if (t2 < 4096) {
            ushort_t* base = (t2 & 1) ? y2p : y1p;
            int r = t2 >> 1;
            int bb = r >> 7;
            int rowsel = (r >> 6) & 1;
            int col = (r & 63) * 8;
            size_t row = (size_t)bb * (T_ + 2) + (rowsel ? (T_ + 1) : 0);
            *(uint4*)&base[row * C_ + col] = (uint4){0, 0, 0, 0};
        }
    }
}

// ---------------- fused adawin instance + leaky-relu ----------------------------
template <int INLAYOUT>
__global__ __launch_bounds__(256) void adawin_kernel(
    const void* __restrict__ xin_, const ushort_t* __restrict__ sw_t,
    const ushort_t* __restrict__ Wfc, const float* __restrict__ fcb,
    const float* __restrict__ alpha, const int* __restrict__ lengths,
    ushort_t* __restrict__ youtp) {
    int t0 = blockIdx.x * 64;
    int c0 = blockIdx.y * 64;
    int b = blockIdx.z;
    __shared__ __attribute__((aligned(16))) ushort_t smem[128 * 136 + 64 * 136];
    ushort_t (*As)[136] = (ushort_t(*)[136])smem;
    ushort_t (*Bs)[136] = (ushort_t(*)[136])(smem + 128 * 136);
    int tid = threadIdx.x;

    {
        int r = tid >> 4;
        int cseg = (tid & 15) * 8;
#pragma unroll
        for (int p = 0; p < 8; ++p) {
            int row = p * 16 + r;
            int grow = (row < 64) ? (c0 + row) : (448 + c0 + row);
            *(uint4*)&As[row][cseg] = *(const uint4*)&Wfc[(size_t)grow * 128 + cseg];
        }
    }
    {
        int tl = tid & 63;
        int sg = tid >> 6;
        const ushort_t* src = &sw_t[((size_t)(b * T_ + t0 + tl)) * S_];
#pragma unroll
        for (int j = 0; j < 4; ++j) {
            int col = sg * 32 + j * 8;
            *(uint4*)&Bs[tl][col] = *(const uint4*)&src[col];
        }
    }
    __syncthreads();

    int wave = tid >> 6, lane = tid & 63;
    int quad = lane >> 4, l = lane & 15;
    f32x4 accg[4], accb[4];
#pragma unroll
    for (int n = 0; n < 4; ++n) {
        accg[n] = (f32x4){0.f, 0.f, 0.f, 0.f};
        accb[n] = (f32x4){0.f, 0.f, 0.f, 0.f};
    }
    int rg = wave * 16 + l;
    int rb = 64 + wave * 16 + l;
#pragma unroll
    for (int ks = 0; ks < 4; ++ks) {
        int kc = ks * 32 + quad * 8;
        bf16x8 ag = *(const bf16x8*)&As[rg][kc];
        bf16x8 ab = *(const bf16x8*)&As[rb][kc];
#pragma unroll
        for (int n = 0; n < 4; ++n) {
            bf16x8 bb = *(const bf16x8*)&Bs[n * 16 + l][kc];
            accg[n] = MFMA16(ag, bb, accg[n]);
            accb[n] = MFMA16(ab, bb, accb[n]);
        }
    }

    __syncthreads();
    ushort_t (*Ts)[72] = (ushort_t(*)[72])smem;

    int len = lengths[b];
    float alph = alpha[0];
    const float* xf = (const float*)xin_;
    const ushort_t* xh = (const ushort_t*)xin_;
    int clocal = wave * 16 + quad * 4;
    int cbase = c0 + clocal;
#pragma unroll
    for (int n = 0; n < 4; ++n) {
        int t = t0 + n * 16 + l;
        int lo = t - HALF; if (lo < 0) lo = 0;
        int hi = t + HALF; if (hi > T_ - 1) hi = T_ - 1;
        float cnt = (float)(hi - lo + 1);
        int hv = hi < (len - 1) ? hi : (len - 1);
        int mdi = hv - lo + 1; if (mdi < 0) mdi = 0;
        float m = (t < len) ? 1.f : 0.f;
        float sc = m / ((float)mdi + 1e-9f);

        float xv[4];
        if (INLAYOUT == 0) {
#pragma unroll
            for (int j = 0; j < 4; ++j)
                xv[j] = xf[(size_t)(b * C_ + cbase + j) * T_ + t];
        } else {
            uint2 xraw = *(const uint2*)&xh[((size_t)(b * (T_ + 2) + 1 + t)) * C_ + cbase];
            xv[0] = bf2f((ushort_t)(xraw.x & 0xffff));
            xv[1] = bf2f((ushort_t)(xraw.x >> 16));
            xv[2] = bf2f((ushort_t)(xraw.y & 0xffff));
            xv[3] = bf2f((ushort_t)(xraw.y >> 16));
        }
        unsigned pk[2];
#pragma unroll
        for (int j = 0; j < 4; ++j) {
            int c = cbase + j;
            float gamma = (accg[n][j] + fcb[c] * cnt) * sc;
            float beta = (accb[n][j] + fcb[C_ + c] * cnt) * sc;
            float xn = fast_tanh(alph * xv[j]);
            float v = (1.f + gamma) * xn + beta;
            v = v > 0.f ? v : 0.2f * v;
            unsigned hv16 = (unsigned)f2bf(v);
            if (j & 1) pk[j >> 1] |= hv16 << 16;
            else pk[j >> 1] = hv16;
        }
        *(uint2*)&Ts[n * 16 + l][clocal] = (uint2){pk[0], pk[1]};
    }
    __syncthreads();
    {
        int row = tid >> 2;
        int seg = (tid & 3) * 16;
        size_t gbase = ((size_t)(b * (T_ + 2) + 1 + t0 + row)) * C_ + c0 + seg;
        *(uint4*)&youtp[gbase] = *(const uint4*)&Ts[row][seg];
        *(uint4*)&youtp[gbase + 8] = *(const uint4*)&Ts[row][seg + 8];
    }
}

// ---------------- conv1d k=3: 128x128 tile, slim LDS -> 3 blocks/CU (TLP) -------
// Block: 256 thr = 4 waves (2o x 2t of 64). Chunk = 16 in-ch x 3 taps; 32 chunks.
// LDS: dbuf of (A 14336 + B 7168) = 43008 B -> 3 co-resident blocks per CU
// (12 waves/CU = 3/SIMD) for latency hiding via independent barrier groups.
// Staging: 21 granules/chunk (wave0: 6, waves1-3: 5); counted boundary wait
// (vmcnt 6/5) completes stage(c) and leaves stage(c+1) in flight.
__device__ __forceinline__ void stage_chunk(const char* img, const char* xt, int cc,
                                            char* Ab, char* Bb, int wave, int lane) {
#pragma unroll
    for (int k = 0; k < 6; ++k) {
        int g = wave + 4 * k;  // 0..23; g>=21 skipped (waves 1-3 issue 5)
        if (g >= 21) continue;
        if (g < 14) {
            glds16(img + g * 1024 + lane * 16, Ab + g * 1024);
        } else {
            int j = g - 14;  // B granule 0..6
            int off = j * 1024 + lane * 16;
            int r = off / 48;
            int sl = (off - r * 48) >> 4;
            if (sl == 2) sl = 0;   // pad slot: benign duplicate
            if (r > 129) r = 129;  // tail: clamp to last valid row
            glds16(xt + (size_t)r * 1024 + cc * 32 + sl * 16, Bb + j * 1024);
        }
    }
}

template <int EPI>
__global__ __launch_bounds__(256, 3) void conv_kernel(
    const ushort_t* __restrict__ Xp, const ushort_t* __restrict__ Wimg,
    const float* __restrict__ bias, const float* __restrict__ resid,
    ushort_t* __restrict__ out_bf, float* __restrict__ out_f) {
    int t0 = blockIdx.x * 128;
    int o0 = blockIdx.y * 128;
    int b = blockIdx.z;
    __shared__ __attribute__((aligned(16))) char smem[2 * CH_BYTES];  // 43008 B
    int tid = threadIdx.x;
    int lane = tid & 63, wave = tid >> 6;
    int l32 = lane & 31, khalf = lane >> 5;
    int wo = (wave & 1) * 64, wt = (wave >> 1) * 64;

    const char* imgbase = (const char*)Wimg + (size_t)blockIdx.y * 32 * ACH_BYTES;
    const char* xt = (const char*)Xp + (size_t)(b * (T_ + 2) + t0) * 1024;  // row r <-> t0-1+r

    f32x16 acc[2][2];  // [io(o-frag)][it(t-frag)]
#pragma unroll
    for (int io = 0; io < 2; ++io)
#pragma unroll
        for (int it = 0; it < 2; ++it)
#pragma unroll
            for (int r = 0; r < 16; ++r) acc[io][it][r] = 0.f;

    stage_chunk(imgbase, xt, 0, smem, smem + ACH_BYTES, wave, lane);

#pragma unroll 1
    for (int c = 0; c < 32; ++c) {
        int cur = c & 1;
        char* Ab = smem + cur * CH_BYTES;
        if (c < 31) {
            char* An = smem + (cur ^ 1) * CH_BYTES;
            stage_chunk(imgbase + (size_t)(c + 1) * ACH_BYTES, xt, c + 1,
                        An, An + ACH_BYTES, wave, lane);
            // counted wait: complete exactly stage(c); stage(c+1) stays in flight
            if (wave == 0) asm volatile("s_waitcnt vmcnt(6)\ns_barrier" ::: "memory");
            else           asm volatile("s_waitcnt vmcnt(5)\ns_barrier" ::: "memory");
        } else {
            asm volatile("s_waitcnt vmcnt(0)\ns_barrier" ::: "memory");
        }
        ushort_t (*As)[56] = (ushort_t(*)[56])Ab;
        ushort_t (*Bs)[24] = (ushort_t(*)[24])(Ab + ACH_BYTES);
#pragma unroll
        for (int p = 0; p < 3; ++p) {
            bf16x8 a0 = *(const bf16x8*)&As[wo + l32][p * 16 + khalf * 8];
            bf16x8 a1 = *(const bf16x8*)&As[wo + 32 + l32][p * 16 + khalf * 8];
            bf16x8 b0 = *(const bf16x8*)&Bs[wt + l32 + p][khalf * 8];
            bf16x8 b1 = *(const bf16x8*)&Bs[wt + 32 + l32 + p][khalf * 8];
            acc[0][0] = MFMA32(a0, b0, acc[0][0]);
            acc[0][1] = MFMA32(a0, b1, acc[0][1]);
            acc[1][0] = MFMA32(a1, b0, acc[1][0]);
            acc[1][1] = MFMA32(a1, b1, acc[1][1]);
        }
        // protect the buffer re-staged next iteration
        asm volatile("s_barrier" ::: "memory");
    }

    // epilogue: C/D layout col=lane&31 (t), row=(reg&3)+8*(reg>>2)+4*khalf (o)
    if (EPI == 0) {
        ushort_t (*Ts)[136] = (ushort_t(*)[136])smem;  // 34816 B fits 43008
#pragma unroll
        for (int io = 0; io < 2; ++io)
#pragma unroll
            for (int it = 0; it < 2; ++it) {
                int trow = wt + it * 32 + l32;
#pragma unroll
                for (int g = 0; g < 4; ++g) {
                    int oc = wo + io * 32 + g * 8 + khalf * 4;
                    unsigned pk[2];
#pragma unroll
                    for (int j = 0; j < 4; ++j) {
                        float v = acc[io][it][g * 4 + j] + bias[o0 + oc + j];
                        unsigned hv16 = (unsigned)f2bf(v);
                        if (j & 1) pk[j >> 1] |= hv16 << 16;
                        else pk[j >> 1] = hv16;
                    }
                    *(uint2*)&Ts[trow][oc] = (uint2){pk[0], pk[1]};
                }
            }
        __syncthreads();
        int cc = (tid & 15) * 8;
        int rbse = tid >> 4;
#pragma unroll
        for (int j = 0; j < 8; ++j) {
            int row = j * 16 + rbse;
            *(uint4*)&out_bf[((size_t)(b * (T_ + 2) + 1 + t0 + row)) * C_ + o0 + cc] =
                *(const uint4*)&Ts[row][cc];
        }
    } else {
#pragma unroll
        for (int io = 0; io < 2; ++io)
#pragma unroll
            for (int it = 0; it < 2; ++it) {
                int obase = o0 + wo + io * 32;
                int t = t0 + wt + it * 32 + l32;
#pragma unroll
                for (int g = 0; g < 4; ++g) {
                    int oo = obase + g * 8 + khalf * 4;
#pragma unroll
                    for (int j = 0; j < 4; ++j) {
                        size_t off = (size_t)(b * C_ + oo + j) * T_ + t;
                        out_f[off] = (acc[io][it][g * 4 + j] + bias[oo + j] + resid[off]) *
                                     0.70710678118654752f;
                    }
                }
            }
    }
}

extern "C" void kernel_launch(void* const* d_in, const int* in_sizes, int n_in,
                              void* d_out, int out_size, void* d_ws, size_t ws_size,
                              hipStream_t stream) {
    const float* x = (const float*)d_in[0];
    const float* s = (const float*)d_in[1];
    const int* lengths = (const int*)d_in[2];
    const float* fc1_w = (const float*)d_in[3];
    const float* fc1_b = (const float*)d_in[4];
    const float* alpha1 = (const float*)d_in[5];
    const float* conv1_w = (const float*)d_in[6];
    const float* conv1_b = (const float*)d_in[7];
    const float* fc2_w = (const float*)d_in[8];
    const float* fc2_b = (const float*)d_in[9];
    const float* alpha2 = (const float*)d_in[10];
    const float* conv2_w = (const float*)d_in[11];
    const float* conv2_b = (const float*)d_in[12];

    const size_t IMGB = (size_t)4 * 32 * ACH_BYTES;  // 1835008 B per conv image
    char* ws = (char*)d_ws;
    ushort_t* sw_t = (ushort_t*)ws; ws += (size_t)B_ * T_ * S_ * 2;        // 8 MB
    ushort_t* Wfc = (ushort_t*)ws;  ws += (size_t)2 * 1024 * 128 * 2;      // 0.5 MB
    ushort_t* I1 = (ushort_t*)ws;   ws += IMGB;                            // 1.84 MB
    ushort_t* I2 = (ushort_t*)ws;   ws += IMGB;                            // 1.84 MB
    ushort_t* y2p = (ushort_t*)ws;  ws += (size_t)B_ * (T_ + 2) * C_ * 2;  // 33.6 MB
    ushort_t* y1p = (ushort_t*)ws;  ws += (size_t)B_ * (T_ + 2) * C_ * 2;  // 33.6 MB
    ws += 12 * 1024;  // glds over-read slack (conv input is always y1p)
    if ((size_t)(ws - (char*)d_ws) > ws_size) return;

    prep_all<<<dim3(2448), dim3(256), 0, stream>>>(
        s, sw_t, fc1_w, fc2_w, Wfc, conv1_w, conv2_w, I1, I2, y1p, y2p);
    adawin_kernel<0><<<dim3(32, 8, 16), dim3(256), 0, stream>>>(
        (const void*)x, sw_t, Wfc, fc1_b, alpha1, lengths, y1p);
    conv_kernel<0><<<dim3(16, 4, 16), dim3(256), 0, stream>>>(
        y1p, I1, conv1_b, (const float*)nullptr, y2p, (float*)nullptr);
    adawin_kernel<1><<<dim3(32, 8, 16), dim3(256), 0, stream>>>(
        (const void*)y2p, sw_t, Wfc + 1024 * 128, fc2_b, alpha2, lengths, y1p);
    conv_kernel<1><<<dim3(16, 4, 16), dim3(256), 0, stream>>>(
        y1p, I2, conv2_b, x, (ushort_t*)nullptr, (float*)d_out);
}